// Round 11
// baseline (3242.414 us; speedup 1.0000x reference)
//
#include <hip/hip_runtime.h>

// Problem constants (B,S,D=16,2048,256; K codebooks=8, CD=1024)
#define DD    256
#define KST   8
#define CDN   1024
#define NROWS 32768          // B*S
#define ROWS  64             // rows (tokens) per block (8 waves x 8 rows)
#define AST   65             // a_t row stride (65: per-lane k-column reads spread banks)

// Transposed codebook, float2-granular:
// cbT[s][c2][j][2] = cb[s][j][2*c2 + 0..1], c2 = 0..127 (k-pair rows).
__device__ float cbT_buf[(size_t)KST * 128 * CDN * 2];   // 8 MB static

__device__ __forceinline__ bool better(float a, int ja, float b, int jb_) {
    return (a < b) || (a == b && ja < jb_);
}

// ---------------------------------------------------------------------------
// numpy AVX512 pairwise sum-of-squares over 256 values (bit-emulated).
template <typename F>
__device__ __forceinline__ float np_sumsq_256(F ld) {
    float Sv = 0.f;
#pragma unroll
    for (int blk = 0; blk < 2; ++blk) {
        const int o = blk * 128;
        float w[16];
#pragma unroll
        for (int l = 0; l < 16; ++l) {
            float v[8];
#pragma unroll
            for (int j = 0; j < 8; ++j) {
                float xv = ld(o + 16 * j + l);
                v[j] = __fmul_rn(xv, xv);
            }
            float a01 = __fadd_rn(v[0], v[1]);
            float a23 = __fadd_rn(v[2], v[3]);
            float a45 = __fadd_rn(v[4], v[5]);
            float a67 = __fadd_rn(v[6], v[7]);
            w[l] = __fadd_rn(__fadd_rn(a01, a23), __fadd_rn(a45, a67));
        }
        float t8[8];
#pragma unroll
        for (int l = 0; l < 8; ++l) t8[l] = __fadd_rn(w[l], w[l + 8]);
        float t4[4];
#pragma unroll
        for (int l = 0; l < 4; ++l) t4[l] = __fadd_rn(t8[l], t8[l + 4]);
        float t2_0 = __fadd_rn(t4[0], t4[2]);
        float t2_1 = __fadd_rn(t4[1], t4[3]);
        float bs = __fadd_rn(t2_0, t2_1);
        Sv = (blk == 0) ? bs : __fadd_rn(Sv, bs);
    }
    return Sv;
}

// ---------------------------------------------------------------------------
__global__ __launch_bounds__(256) void norms_kernel(const float* __restrict__ cb,
                                                    float* __restrict__ n32) {
    int j = blockIdx.x * 256 + threadIdx.x;   // 0..8191
    const float* p = cb + (size_t)j * DD;
    n32[j] = np_sumsq_256([&](int i) { return p[i]; });
}

// ---------------------------------------------------------------------------
// One-time codebook transpose into cbT_buf (float2 granules).
__global__ __launch_bounds__(256) void tr_kernel(const float* __restrict__ cb) {
    int idx = blockIdx.x * 256 + threadIdx.x;  // 0 .. 1048575
    int j  = idx & 1023;
    int c2 = (idx >> 10) & 127;
    int s  = idx >> 17;
    float2 v = *(const float2*)(cb + ((size_t)(s * CDN + j) * DD) + c2 * 2);
    *(float2*)(cbT_buf + (size_t)idx * 2) = v;
}

// ---------------------------------------------------------------------------
// Fused RVQ — numpy-fp32 emulation, L2-traffic-shared structure.
// Rounds 4-9 plateaued at VALUBusy 45-49% independent of occupancy: each wave
// privately streamed the full 1MB codebook slab from L2 (8x redundancy per
// block; ~33GB L2 reads; demand 64 B/cyc/CU vs ~56 available) -> L2-BW-bound.
// This round: B staged in LDS per block (16KB tiles, 8 k-pairs x 512 cw,
// double-buffered, reg-staged with issue-early/write-late) -> L2 B-traffic /8.
// A moves OFF the LDS pipe: lane cg holds aQ[r]=a_t[q*64+cg][row]; the
// wave-uniform a[r][k] comes from v_readlane(aQ[r], k&63) (VALU, zero LDS).
// Per-CU-per-k budget: LDS ~215cy (B b128 + staging) < VALU ~296cy -> VALU-
// bound, FMA 86% of issue. Lane owns 8 CONTIGUOUS cw (j = h*512 + cg*8 + sl)
// so B reads are conflict-free ds_read_b128.
// Exactness: per-(row,cw) dot = single-accumulator FMA chain, k ascending
// (tile asc x kp asc x kk asc); score compose + lexicographic argmin
// unchanged -> outputs bit-identical to prior passing rounds.
__global__ __launch_bounds__(512, 2) void rvq_kernel(const float* __restrict__ x,
                                                     const float* __restrict__ cbs,
                                                     const float* __restrict__ n32,
                                                     float* __restrict__ out) {
    __shared__ __align__(16) float a_t[DD][AST];       // 66560 B residual^T
    __shared__ __align__(16) float Bl[2][8][512][2];   // 65536 B dbuf B tiles
    __shared__ float rowS[ROWS];
    __shared__ float bestS[ROWS];
    __shared__ int   bestI[ROWS];
    __shared__ float wred[8];

    const int tid  = threadIdx.x;
    const int base = blockIdx.x * ROWS;
    const int cg   = tid & 63;            // lane
    const int ty   = tid >> 6;            // wave id = row-group (8 rows), 0..7
    const int row0 = ty * 8;
    const int urow = tid & 63;            // update row
    const int ug   = tid >> 6;            // owned 32-dim segment

    for (int i = tid; i < ROWS * DD / 4; i += 512) {
        int row = i >> 6;
        int dq  = i & 63;
        float4 v = ((const float4*)(x + (size_t)(base + row) * DD))[dq];
        int d = dq * 4;
        a_t[d + 0][row] = v.x; a_t[d + 1][row] = v.y;
        a_t[d + 2][row] = v.z; a_t[d + 3][row] = v.w;
    }

    float loss_acc = 0.f;
    const int hi8 = tid >> 8;             // 0/1: which kp of each staged pair
    const int rem = tid & 255;            // position within a kp half-row

    for (int s = 0; s < KST; ++s) {
        const float* cb  = cbs + (size_t)s * CDN * DD;
        const float* nr  = n32 + s * CDN;
        const float* cts = cbT_buf + ((size_t)s << 18);
        __syncthreads();                  // (A) a_t stable; prev bestI reads done

        if (cg < 8) {                     // wave-local rows: sumsq + best init
            int row = row0 + cg;
            rowS[row] = np_sumsq_256([&](int i) { return a_t[i][row]; });
            bestS[row] = 3.4e38f;
            bestI[row] = 0x7ffffff;
        }

        for (int h = 0; h < 2; ++h) {
            __syncthreads();              // Bl free (prev h/stage compute done)

            float4 stg[4];
            // prologue: stage tile 0 -> buf 0 (tile = 8 kp x 512 cw = 16KB)
#pragma unroll
            for (int i = 0; i < 4; ++i) {
                int kp = hi8 + 2 * i;
                stg[i] = *(const float4*)(cts + (size_t)kp * 2048 + h * 1024 + rem * 4);
            }
#pragma unroll
            for (int i = 0; i < 4; ++i)
                ((float4*)&Bl[0][0][0][0])[tid + i * 512] = stg[i];

            int cur = 0;
            float acc[8][8];              // [slot][r]
#pragma unroll
            for (int sl = 0; sl < 8; ++sl)
#pragma unroll
                for (int r = 0; r < 8; ++r) acc[sl][r] = 0.f;
            float aQ[8];                  // lane's k-column of its wave's 8 rows

#pragma unroll 1
            for (int t = 0; t < 16; ++t) {
                __syncthreads();          // Bl[cur] staged+visible; Bl[cur^1] free
                if ((t & 3) == 0) {       // new 64-k block: reload A column
                    int q = t >> 2;
#pragma unroll
                    for (int r = 0; r < 8; ++r)
                        aQ[r] = a_t[q * 64 + cg][row0 + r];
                }
                if (t < 15) {             // issue next tile's loads early
#pragma unroll
                    for (int i = 0; i < 4; ++i) {
                        int kp = hi8 + 2 * i;
                        stg[i] = *(const float4*)(cts + (size_t)((t + 1) * 8 + kp) * 2048
                                                      + h * 1024 + rem * 4);
                    }
                }
                // compute tile t: 8 kp x 2 k; B = 4 b128/kp, A via readlane
#pragma unroll
                for (int kp = 0; kp < 8; ++kp) {
                    const float4* bp4 = (const float4*)&Bl[cur][kp][cg * 8][0];
                    float4 b0 = bp4[0], b1 = bp4[1], b2 = bp4[2], b3 = bp4[3];
                    float bk0[8] = {b0.x, b0.z, b1.x, b1.z, b2.x, b2.z, b3.x, b3.z};
                    float bk1[8] = {b0.y, b0.w, b1.y, b1.w, b2.y, b2.w, b3.y, b3.w};
#pragma unroll
                    for (int kk = 0; kk < 2; ++kk) {
                        int ln = (t & 3) * 16 + kp * 2 + kk;   // k & 63 (uniform)
                        float ar[8];
#pragma unroll
                        for (int r = 0; r < 8; ++r)
                            ar[r] = __int_as_float(
                                __builtin_amdgcn_readlane(__float_as_int(aQ[r]), ln));
                        const float* bsel = kk ? bk1 : bk0;
#pragma unroll
                        for (int sl = 0; sl < 8; ++sl)
#pragma unroll
                            for (int r = 0; r < 8; ++r)
                                acc[sl][r] = __builtin_fmaf(bsel[sl], ar[r], acc[sl][r]);
                    }
                }
                if (t < 15) {             // write-late: loads had compute to land
#pragma unroll
                    for (int i = 0; i < 4; ++i)
                        ((float4*)&Bl[cur ^ 1][0][0][0])[tid + i * 512] = stg[i];
                }
                cur ^= 1;
            }

            // np-composed score + per-row 64-lane argmin butterfly
            const float* nrp = nr + h * 512 + cg * 8;
            float4 nA = *(const float4*)nrp;
            float4 nB = *(const float4*)(nrp + 4);
            float nrv[8] = {nA.x, nA.y, nA.z, nA.w, nB.x, nB.y, nB.z, nB.w};
#pragma unroll
            for (int r = 0; r < 8; ++r) {
                int row = row0 + r;
                float Sr = rowS[row];
                float t1 = 3.4e38f; int u1 = 0x7ffffff;
#pragma unroll
                for (int sl = 0; sl < 8; ++sl) {
                    int j = h * 512 + cg * 8 + sl;
                    float m2 = __fmul_rn(2.f, acc[sl][r]);
                    float sc2 = __fadd_rn(__fsub_rn(Sr, m2), nrv[sl]);
                    if (better(sc2, j, t1, u1)) { t1 = sc2; u1 = j; }
                }
#pragma unroll
                for (int off = 32; off >= 1; off >>= 1) {
                    float ob = __shfl_xor(t1, off, 64);
                    int   oj = __shfl_xor(u1, off, 64);
                    if (better(ob, oj, t1, u1)) { t1 = ob; u1 = oj; }
                }
                if (cg == r) {            // wave owns the row: no merge
                    if (better(t1, u1, bestS[row], bestI[row])) {
                        bestS[row] = t1; bestI[row] = u1;
                    }
                }
            }
        }

        if (cg < 8) {                     // index output, wave-local rows
            int row = row0 + cg;
            out[2 + (size_t)(base + row) * KST + s] = (float)bestI[row];
        }
        __syncthreads();                  // (C) bestI final for all rows

        // residual update + loss (elementwise fp32)
        {
            int bi = bestI[urow];
            const float4* cp = (const float4*)(cb + (size_t)bi * DD + ug * 32);
#pragma unroll
            for (int dq = 0; dq < 8; ++dq) {
                float4 v = cp[dq];
                int d = ug * 32 + dq * 4;
                float e0 = __fsub_rn(a_t[d + 0][urow], v.x); a_t[d + 0][urow] = e0;
                float e1 = __fsub_rn(a_t[d + 1][urow], v.y); a_t[d + 1][urow] = e1;
                float e2 = __fsub_rn(a_t[d + 2][urow], v.z); a_t[d + 2][urow] = e2;
                float e3 = __fsub_rn(a_t[d + 3][urow], v.w); a_t[d + 3][urow] = e3;
                loss_acc += e0 * e0 + e1 * e1 + e2 * e2 + e3 * e3;
            }
        }
    }
    __syncthreads();                      // (E) a_t final

    // ---- outputs ---- (indices already written per stage)
    float* q = out + 2 + (size_t)NROWS * KST;
    for (int i = tid; i < ROWS * DD / 4; i += 512) {
        int row = i >> 6, dq = i & 63, d = dq * 4;
        float4 xv = ((const float4*)(x + (size_t)(base + row) * DD))[dq];
        float4 o;
        o.x = xv.x - a_t[d + 0][row];
        o.y = xv.y - a_t[d + 1][row];
        o.z = xv.z - a_t[d + 2][row];
        o.w = xv.w - a_t[d + 3][row];
        ((float4*)(q + (size_t)(base + row) * DD))[dq] = o;
    }
#pragma unroll
    for (int off = 32; off >= 1; off >>= 1) loss_acc += __shfl_down(loss_acc, off, 64);
    if ((tid & 63) == 0) wred[tid >> 6] = loss_acc;
    __syncthreads();
    if (tid == 0) {
        float t = ((wred[0] + wred[1]) + (wred[2] + wred[3]))
                + ((wred[4] + wred[5]) + (wred[6] + wred[7]));
        t *= (1.f / ((float)NROWS * (float)DD));
        atomicAdd(out + 0, t);
        atomicAdd(out + 1, t);
    }
}

// ---------------------------------------------------------------------------
extern "C" void kernel_launch(void* const* d_in, const int* in_sizes, int n_in,
                              void* d_out, int out_size, void* d_ws, size_t ws_size,
                              hipStream_t stream) {
    const float* x   = (const float*)d_in[0];   // [16,2048,256] fp32
    const float* cbs = (const float*)d_in[1];   // [8,1024,256] fp32
    float* out = (float*)d_out;
    float* n32 = (float*)d_ws;                  // 8192 floats

    hipMemsetAsync(d_out, 0, 2 * sizeof(float), stream);
    tr_kernel<<<4096, 256, 0, stream>>>(cbs);
    norms_kernel<<<32, 256, 0, stream>>>(cbs, n32);
    rvq_kernel<<<NROWS / ROWS, 512, 0, stream>>>(x, cbs, n32, out);
}